// Round 6
// baseline (1811.869 us; speedup 1.0000x reference)
//
#include <hip/hip_runtime.h>

// ForexLSTM: 2-layer LSTM (B=1024, T=512, D=14, H=128) + batchnorm-over-batch + MLP(128->32->1)
//
// Round 5: merge the two per-step phases into ONE (software-pipeline the layers).
// L0 at time p and L1 at time p-1 share dependencies {h1(p-1), h2(p-2), x(p)} ->
// compute both in a single phase with a single barrier (513 phases, predicated ends).
//   - 4 h1f fragment reads SHARED between Whh0 (L0) and Wih1 (L1): 13 b128/wave/phase vs 17.
//   - 1 barrier/step instead of 2; both layers' MFMA + transcendental chains interleave.
//   - Everything else as validated R4: weights as A-frags in regs (Whh1-kt3 in LDS),
//     D[row=gate,col=batch], in-register act/state, h in B-frag LDS layout, bias0 folded
//     into Wih0 via x_aug[15]=1.

#define B_ 1024
#define T_ 512
#define D_ 14
#define H_ 128
#define NB 4
#define NT 512

typedef _Float16 f16;
typedef _Float16 half4 __attribute__((ext_vector_type(4)));
typedef _Float16 half8 __attribute__((ext_vector_type(8)));
typedef _Float16 f16x2 __attribute__((ext_vector_type(2)));
typedef float floatx4 __attribute__((ext_vector_type(4)));

__device__ __forceinline__ float fexp(float x) {
    return __builtin_amdgcn_exp2f(x * 1.44269504088896f);
}
__device__ __forceinline__ float sigm(float x) {
    return __builtin_amdgcn_rcpf(1.0f + fexp(-x));
}
__device__ __forceinline__ float tanh_(float x) {
    return 1.0f - 2.0f * __builtin_amdgcn_rcpf(1.0f + fexp(2.0f * x));
}

__device__ __forceinline__ half8 ldfrag(const float* __restrict__ p) {
    half8 r;
#pragma unroll
    for (int j = 0; j < 8; ++j) r[j] = (f16)p[j];
    return r;
}

#define MFMA(a, b, c) __builtin_amdgcn_mfma_f32_16x16x32_f16((a), (b), (c), 0, 0, 0)

__global__ __launch_bounds__(NT, 2) void lstm_fused(
    const float* __restrict__ x,
    const float* __restrict__ Wih0, const float* __restrict__ Whh0,
    const float* __restrict__ bih0, const float* __restrict__ bhh0,
    const float* __restrict__ Wih1, const float* __restrict__ Whh1,
    const float* __restrict__ bih1, const float* __restrict__ bhh1,
    float* __restrict__ h2last)
{
    // LDS: 32 + 8 + 8 + 2 = 50 KB
    __shared__ __align__(16) f16 whh1k3[32][64][8];   // Whh1 kt3 A-frags, [ni*8+wv][lane][e]
    __shared__ __align__(16) f16 h1f[2][4][64][8];    // [buf][kt][lane][e] B-frag layout
    __shared__ __align__(16) f16 h2f[2][4][64][8];
    __shared__ __align__(16) f16 xf[2][64][8];        // x_aug B-frags (K=16: 14 x, 0, 1.0)

    const int tid = threadIdx.x;
    const int lane = tid & 63;
    const int wv = tid >> 6;        // wave 0..7 = j-group
    const int n = lane & 15;        // batch column (valid < NB) / A-row index
    const int q = lane >> 4;        // quad -> D rows q*4+r
    const int b0 = blockIdx.x * NB;
    const int jg = wv * 16;         // j-group base
    // h write-back target: j = jg + q*4 + r -> kt=wv>>1, lane slot n+16*qw, elem eb+r
    const int ktw = wv >> 1;
    const int qw = (wv & 1) * 2 + (q >> 1);
    const int eb = (q & 1) * 4;

    // ---- weights into registers as A-frags: A[m=lane&15][k=q*8+e] ----
    half8 aWhh0[4][4], aWih1[4][4], aWhh1[4][3], aWih0[4];
    f16x2 b1p[4][2];   // layer-1 bias for rows q*4+{0..3}, per gate

#pragma unroll
    for (int ni = 0; ni < 4; ++ni) {
        const int g = ni * 128 + jg + n;
#pragma unroll
        for (int kt = 0; kt < 4; ++kt) {
            const int cb = kt * 32 + q * 8;
            aWhh0[ni][kt] = ldfrag(Whh0 + (size_t)g * H_ + cb);
            aWih1[ni][kt] = ldfrag(Wih1 + (size_t)g * H_ + cb);
            if (kt < 3) {
                aWhh1[ni][kt] = ldfrag(Whh1 + (size_t)g * H_ + cb);
            } else {
                half8 t3 = ldfrag(Whh1 + (size_t)g * H_ + cb);
                *(half8*)&whh1k3[ni * 8 + wv][lane][0] = t3;
            }
        }
        // Wih0 augmented: k<14 = W, k==15 = bias0, k==14 = 0
        half8 w0;
#pragma unroll
        for (int e = 0; e < 8; ++e) {
            int k = q * 8 + e;
            if (k < D_)       w0[e] = (f16)Wih0[(size_t)g * D_ + k];
            else if (k == 15) w0[e] = (f16)(bih0[g] + bhh0[g]);
            else              w0[e] = (f16)0.0f;
        }
        aWih0[ni] = w0;
        const int gb = ni * 128 + jg + q * 4;
        f16x2 p0, p1;
        p0[0] = (f16)(bih1[gb]     + bhh1[gb]);
        p0[1] = (f16)(bih1[gb + 1] + bhh1[gb + 1]);
        p1[0] = (f16)(bih1[gb + 2] + bhh1[gb + 2]);
        p1[1] = (f16)(bih1[gb + 3] + bhh1[gb + 3]);
        b1p[ni][0] = p0;
        b1p[ni][1] = p1;
    }

    // ---- zero state buffers: h1f+h2f = 16 KB = 4096 dwords, xf = 2 KB = 512 dwords ----
#pragma unroll
    for (int i = 0; i < 4; ++i) {
        ((unsigned int*)h1f)[tid + i * 512] = 0u;
        ((unsigned int*)h2f)[tid + i * 512] = 0u;
    }
    ((unsigned int*)xf)[tid] = 0u;
    __syncthreads();

    // ---- x_aug constants (k==15 -> 1.0 in BOTH buffers) + stage x(0) into xf[0] ----
    if (tid < NB) {
        xf[0][tid + 16][7] = (f16)1.0f;
        xf[1][tid + 16][7] = (f16)1.0f;
    }
    if (tid < 64) {
        int nn = tid & 15, kq = tid >> 4;
        if (nn < NB && kq < 2) {   // k = kq*8+e, only k<14 have data
            half8 v;
#pragma unroll
            for (int e = 0; e < 8; ++e) {
                int k = kq * 8 + e;
                v[e] = (k < D_) ? (f16)x[(size_t)(b0 + nn) * T_ * D_ + k]
                                : (k == 15 ? (f16)1.0f : (f16)0.0f);
            }
            *(half8*)&xf[0][tid][0] = v;
        }
    }

    floatx4 c1 = {0.f, 0.f, 0.f, 0.f}, c2 = {0.f, 0.f, 0.f, 0.f};
    __syncthreads();

    // ======== 513 merged phases: phase p computes L0(t=p) and L1(t=p-1) ========
    for (int p = 0; p <= T_; ++p) {
        const int cur = p & 1, nxt = cur ^ 1;
        const bool doL0 = (p < T_);
        const bool doL1 = (p > 0);

        // x(p+1) prefetch into a register (staged before the barrier)
        float xp = 0.0f;
        if (tid < NB * D_ && (p + 1) < T_)
            xp = x[(size_t)(b0 + (tid & 3)) * T_ * D_ + (size_t)(p + 1) * D_ + (tid >> 2)];

        floatx4 C0[4], C1[4];
#pragma unroll
        for (int ni = 0; ni < 4; ++ni) {
            C0[ni] = floatx4{0.f, 0.f, 0.f, 0.f};
            C1[ni] = floatx4{0.f, 0.f, 0.f, 0.f};
        }

        if (doL0) {
            half8 bx = *(const half8*)&xf[cur][lane][0];
#pragma unroll
            for (int ni = 0; ni < 4; ++ni) C0[ni] = MFMA(aWih0[ni], bx, C0[ni]);
        }
        // shared h1(p-1) loop: feeds BOTH Whh0 (L0) and Wih1 (L1)
#pragma unroll
        for (int kt = 0; kt < 4; ++kt) {
            half8 bh = *(const half8*)&h1f[cur][kt][lane][0];
            if (doL0) {
#pragma unroll
                for (int ni = 0; ni < 4; ++ni) C0[ni] = MFMA(aWhh0[ni][kt], bh, C0[ni]);
            }
            if (doL1) {
#pragma unroll
                for (int ni = 0; ni < 4; ++ni) C1[ni] = MFMA(aWih1[ni][kt], bh, C1[ni]);
            }
        }
        if (doL1) {
#pragma unroll
            for (int kt = 0; kt < 3; ++kt) {
                half8 bh = *(const half8*)&h2f[cur][kt][lane][0];
#pragma unroll
                for (int ni = 0; ni < 4; ++ni) C1[ni] = MFMA(aWhh1[ni][kt], bh, C1[ni]);
            }
            half8 bh = *(const half8*)&h2f[cur][3][lane][0];
#pragma unroll
            for (int ni = 0; ni < 4; ++ni) {
                half8 aw = *(const half8*)&whh1k3[ni * 8 + wv][lane][0];
                C1[ni] = MFMA(aw, bh, C1[ni]);
            }
        }

        // ---- L0 act + c1 update + h1(p) write ----
        if (doL0) {
            half4 hp;
#pragma unroll
            for (int r = 0; r < 4; ++r) {
                float i_ = sigm(C0[0][r]);
                float f_ = sigm(C0[1][r]);
                float g_ = tanh_(C0[2][r]);
                float o_ = sigm(C0[3][r]);
                c1[r] = f_ * c1[r] + i_ * g_;
                hp[r] = (f16)(o_ * tanh_(c1[r]));
            }
            if (n < NB) *(half4*)&h1f[nxt][ktw][n + 16 * qw][eb] = hp;
        }
        // ---- L1 act + c2 update + h2(p-1) write ----
        if (doL1) {
            half4 hp;
            floatx4 hv;
#pragma unroll
            for (int r = 0; r < 4; ++r) {
                float pi = C1[0][r] + (float)b1p[0][r >> 1][r & 1];
                float pf = C1[1][r] + (float)b1p[1][r >> 1][r & 1];
                float pg = C1[2][r] + (float)b1p[2][r >> 1][r & 1];
                float po = C1[3][r] + (float)b1p[3][r >> 1][r & 1];
                float i_ = sigm(pi), f_ = sigm(pf), g_ = tanh_(pg), o_ = sigm(po);
                c2[r] = f_ * c2[r] + i_ * g_;
                hv[r] = o_ * tanh_(c2[r]);
                hp[r] = (f16)hv[r];
            }
            if (n < NB) {
                *(half4*)&h2f[nxt][ktw][n + 16 * qw][eb] = hp;
                if (p == T_) {
#pragma unroll
                    for (int r = 0; r < 4; ++r)
                        h2last[(size_t)(b0 + n) * H_ + jg + q * 4 + r] = hv[r];
                }
            }
        }
        // restage x(p+1) (k slots 0..13; 14/15 constant from init)
        if (tid < NB * D_ && (p + 1) < T_) {
            int k = tid >> 2;
            xf[nxt][(tid & 3) + 16 * (k >> 3)][k & 7] = (f16)xp;
        }
        __syncthreads();
    }
}

// batch-norm statistics over the batch dim: 1 block, 1024 threads
__global__ void bn_stats(const float* __restrict__ h2last, float* __restrict__ stats)
{
    __shared__ float red[2][8][128];
    const int tid = threadIdx.x;
    const int j = tid & 127, bs = tid >> 7;
    float s = 0.0f, ss = 0.0f;
    for (int bb = 0; bb < 128; ++bb) {
        float v = h2last[(size_t)(bb * 8 + bs) * H_ + j];
        s += v;
        ss += v * v;
    }
    red[0][bs][j] = s;
    red[1][bs][j] = ss;
    __syncthreads();
    if (tid < 128) {
        float S = 0.0f, SS = 0.0f;
#pragma unroll
        for (int k = 0; k < 8; ++k) { S += red[0][k][tid]; SS += red[1][k][tid]; }
        float mu = S * (1.0f / 1024.0f);
        float var = SS * (1.0f / 1024.0f) - mu * mu;
        stats[tid] = mu;
        stats[128 + tid] = __builtin_amdgcn_rsqf(var + 1e-5f);
    }
}

// normalize + MLP head: 8 blocks x 128 threads, one batch element per thread
__global__ void bn_mlp(const float* __restrict__ h2last, const float* __restrict__ stats,
                       const float* __restrict__ gamma, const float* __restrict__ beta,
                       const float* __restrict__ W1, const float* __restrict__ b1,
                       const float* __restrict__ W2, const float* __restrict__ b2,
                       float* __restrict__ out)
{
    __shared__ float W1T[128][33];
    __shared__ float mus[128], isds[128], gs[128], bts[128], w2s[32];
    const int tid = threadIdx.x;
    const int b = blockIdx.x * 128 + tid;

    for (int i = tid; i < 4096; i += 128) {
        int k = i >> 7, j = i & 127;
        W1T[j][k] = W1[i];
    }
    mus[tid] = stats[tid];
    isds[tid] = stats[128 + tid];
    gs[tid] = gamma[tid];
    bts[tid] = beta[tid];
    if (tid < 32) w2s[tid] = W2[tid];
    __syncthreads();

    float z[32];
#pragma unroll
    for (int k = 0; k < 32; ++k) z[k] = b1[k];

    for (int j = 0; j < 128; ++j) {
        float nv = (h2last[(size_t)b * H_ + j] - mus[j]) * isds[j] * gs[j] + bts[j];
#pragma unroll
        for (int k = 0; k < 32; ++k) z[k] += W1T[j][k] * nv;
    }
    float o = b2[0];
#pragma unroll
    for (int k = 0; k < 32; ++k) o += w2s[k] * fmaxf(z[k], 0.0f);
    out[b] = o;
}

extern "C" void kernel_launch(void* const* d_in, const int* in_sizes, int n_in,
                              void* d_out, int out_size, void* d_ws, size_t ws_size,
                              hipStream_t stream)
{
    const float* x    = (const float*)d_in[0];
    const float* Wih0 = (const float*)d_in[1];
    const float* Whh0 = (const float*)d_in[2];
    const float* bih0 = (const float*)d_in[3];
    const float* bhh0 = (const float*)d_in[4];
    const float* Wih1 = (const float*)d_in[5];
    const float* Whh1 = (const float*)d_in[6];
    const float* bih1 = (const float*)d_in[7];
    const float* bhh1 = (const float*)d_in[8];
    const float* gamma = (const float*)d_in[9];
    const float* beta  = (const float*)d_in[10];
    const float* W1 = (const float*)d_in[11];
    const float* b1 = (const float*)d_in[12];
    const float* W2 = (const float*)d_in[13];
    const float* b2 = (const float*)d_in[14];

    float* h2last = (float*)d_ws;              // 1024*128 floats = 512 KB
    float* stats  = h2last + (size_t)B_ * H_;  // 256 floats
    float* out = (float*)d_out;

    hipLaunchKernelGGL(lstm_fused, dim3(B_ / NB), dim3(NT), 0, stream,
                       x, Wih0, Whh0, bih0, bhh0, Wih1, Whh1, bih1, bhh1, h2last);
    hipLaunchKernelGGL(bn_stats, dim3(1), dim3(1024), 0, stream, h2last, stats);
    hipLaunchKernelGGL(bn_mlp, dim3(8), dim3(128), 0, stream,
                       h2last, stats, gamma, beta, W1, b1, W2, b2, out);
}